// Round 4
// baseline (244.849 us; speedup 1.0000x reference)
//
#include <hip/hip_runtime.h>
#include <hip/hip_bf16.h>
#include <math.h>

#define B_  4
#define S_  2048
#define H_  512
#define NH_ 8
#define D_  64

typedef __attribute__((ext_vector_type(8))) short bf16x8;   // 8 bf16 = 4 VGPR
typedef __attribute__((ext_vector_type(4))) float f32x4;
typedef __attribute__((ext_vector_type(16))) float f32x16;
#define MFMA16(a, b, c) __builtin_amdgcn_mfma_f32_16x16x32_bf16(a, b, c, 0, 0, 0)
#define MFMA32(a, b, c) __builtin_amdgcn_mfma_f32_32x32x16_bf16(a, b, c, 0, 0, 0)

__device__ __forceinline__ unsigned short f2bf(float f) {
    union { float f; unsigned int i; } x; x.f = f;
    unsigned int i = x.i;
    i += 0x7fffu + ((i >> 16) & 1u);
    return (unsigned short)(i >> 16);
}
// packed fp32 pair -> bf16 pair (RNE), lo in low 16 bits
__device__ __forceinline__ unsigned int pk2(float lo, float hi) {
    union { __hip_bfloat162 h; unsigned int u; } c;
    c.h = __float22bfloat162_rn(make_float2(lo, hi));
    return c.u;
}
// async global->LDS, 16 B per lane; lds ptr must be wave-uniform
__device__ __forceinline__ void gl_lds16(const void* g, void* l) {
    __builtin_amdgcn_global_load_lds(
        (const __attribute__((address_space(1))) unsigned int*)g,
        (__attribute__((address_space(3))) unsigned int*)l, 16, 0, 0);
}

// ---------------------------------------------------------------------------
// Weight prep: transpose+convert 512x512 fp32 W -> bf16 Wt[n][k] (n-major).
// ---------------------------------------------------------------------------
__global__ __launch_bounds__(256) void prep_w(
    const float* __restrict__ W0, const float* __restrict__ W1,
    const float* __restrict__ W2, const float* __restrict__ W3,
    unsigned short* __restrict__ Wt)
{
    const float* Ws[4] = {W0, W1, W2, W3};
    const float* W = Ws[blockIdx.z];
    unsigned short* Y = Wt + (size_t)blockIdx.z * H_ * H_;
    __shared__ float Tl[64][68];
    const int t = threadIdx.x;
    const int k0 = blockIdx.y * 64, n0 = blockIdx.x * 64;
    #pragma unroll
    for (int i = 0; i < 4; ++i) {
        const int e = (t + 256 * i) * 4;
        const int r = e >> 6, c = e & 63;
        const float4 a = *(const float4*)(W + (size_t)(k0 + r) * H_ + n0 + c);
        Tl[c + 0][r] = a.x; Tl[c + 1][r] = a.y;
        Tl[c + 2][r] = a.z; Tl[c + 3][r] = a.w;
    }
    __syncthreads();
    #pragma unroll
    for (int i = 0; i < 4; ++i) {
        const int e = (t + 256 * i) * 4;
        const int n = e >> 6, c = e & 63;
        uint2 p;
        p.x = pk2(Tl[n][c + 0], Tl[n][c + 1]);
        p.y = pk2(Tl[n][c + 2], Tl[n][c + 3]);
        *(uint2*)(Y + (size_t)(n0 + n) * H_ + k0 + c) = p;
    }
}

// ---------------------------------------------------------------------------
// Fused projections v3: z=0 Q, z=1 K (dual), z=2 V (transposed epilogue).
// Tile 128x128, K-step 64, 2x2 wave quadrants, acc[4][4].
// DOUBLE-BUFFERED, ONE barrier per K-step (attn-proven structure):
//   issue gload_lds B(t+1) + float4 A(t+1) loads BEFORE the MFMA phase of t,
//   cvt+ds_write A(t+1) AFTER MFMA (issue-early / write-late), barrier.
// Staging latency hides under the 32-MFMA compute phase.
// LDS 64KB -> 2 blocks/CU.
// ---------------------------------------------------------------------------
__global__ __launch_bounds__(256, 2) void proj_all(
    const float* __restrict__ q,  const float* __restrict__ k,
    const float* __restrict__ v,  const float* __restrict__ k_b,
    const unsigned short* __restrict__ Wt,
    const float* __restrict__ bq, const float* __restrict__ bk,
    const float* __restrict__ bkb,const float* __restrict__ bv,
    unsigned short* __restrict__ Qf, unsigned short* __restrict__ Kf,
    unsigned short* __restrict__ Vf)
{
    // Pool: As0 | Bs0 | As1 | Bs1 (8192 halfs each). VT epilogue reuses
    // the first 17408 halfs as a [128][136] transpose buffer.
    __shared__ __align__(16) unsigned short LB[32768];      // 64 KB

    const int z = blockIdx.z;
    const float *X, *bias, *X2 = nullptr, *bias2 = nullptr;
    const unsigned short *Wa, *Wb = nullptr;
    unsigned short* Y;
    bool VT = false;
    const size_t WSZ = (size_t)H_ * H_;
    if (z == 0)      { X = q; Wa = Wt;           bias = bq; Y = Qf; }
    else if (z == 1) { X = k; Wa = Wt + WSZ;     bias = bk;
                       X2 = k_b; Wb = Wt + 2 * WSZ; bias2 = bkb; Y = Kf; }
    else             { X = v; Wa = Wt + 3 * WSZ; bias = bv; Y = Vf; VT = true; }

    const int t = threadIdx.x;
    const int w = t >> 6, lane = t & 63;
    const int quad = lane >> 4, l15 = lane & 15;
    const int wr = w >> 1, wc = w & 1;
    const int m0 = blockIdx.x * 128, n0 = blockIdx.y * 128;

    const f32x4 zero = {0.f, 0.f, 0.f, 0.f};
    f32x4 acc[4][4];
    #pragma unroll
    for (int i = 0; i < 4; ++i)
        #pragma unroll
        for (int j = 0; j < 4; ++j) acc[i][j] = zero;

    const int NS = (X2 != nullptr) ? 16 : 8;    // K-steps (2 passes for z=1)

    // ---- staging helpers (step s, buffer bfx) ----
    #define STAGE_B(s_, bfx_) do {                                             \
        const unsigned short* Wp_ = ((s_) >> 3) ? Wb : Wa;                     \
        const int kb0_ = ((s_) & 7) * 64;                                      \
        unsigned short* Bd_ = LB + (bfx_) * 16384 + 8192;                      \
        _Pragma("unroll")                                                      \
        for (int i_ = 0; i_ < 4; ++i_) {                                       \
            const int c_ = w * 4 + i_;                                         \
            const int u_ = c_ * 64 + lane;                                     \
            const int row_ = u_ >> 3;                                          \
            const int sc_ = ((u_ & 7) ^ (row_ & 7)) << 3;                      \
            gl_lds16(Wp_ + (size_t)(n0 + row_) * H_ + kb0_ + sc_,              \
                     Bd_ + c_ * 512);                                          \
        }                                                                      \
    } while (0)

    #define LOAD_A(av_, s_) do {                                               \
        const float* Xp_ = ((s_) >> 3) ? X2 : X;                               \
        const int kb0_ = ((s_) & 7) * 64;                                      \
        _Pragma("unroll")                                                      \
        for (int i_ = 0; i_ < 8; ++i_) {                                       \
            const int e_ = (t + 256 * i_) * 4;                                 \
            av_[i_] = *(const float4*)(Xp_ + (size_t)(m0 + (e_ >> 6)) * H_     \
                                       + kb0_ + (e_ & 63));                    \
        }                                                                      \
    } while (0)

    #define CVT_WRITE_A(av_, bfx_) do {                                        \
        unsigned short* Ad_ = LB + (bfx_) * 16384;                             \
        _Pragma("unroll")                                                      \
        for (int i_ = 0; i_ < 8; ++i_) {                                       \
            const int e_ = (t + 256 * i_) * 4;                                 \
            const int row_ = e_ >> 6, kc_ = e_ & 63;                           \
            uint2 p_; p_.x = pk2(av_[i_].x, av_[i_].y);                        \
            p_.y = pk2(av_[i_].z, av_[i_].w);                                  \
            *(uint2*)&Ad_[row_ * 64 +                                          \
                ((((kc_ >> 3) ^ (row_ & 7)) << 3) | (kc_ & 7))] = p_;          \
        }                                                                      \
    } while (0)

    // ---- prologue: fully stage step 0 into buffer 0 ----
    float4 av[8];
    STAGE_B(0, 0);
    LOAD_A(av, 0);
    CVT_WRITE_A(av, 0);
    __syncthreads();

    for (int s = 0; s < NS; ++s) {
        const int cur = s & 1, nxt = cur ^ 1;
        const bool more = (s + 1 < NS);
        if (more) { STAGE_B(s + 1, nxt); LOAD_A(av, s + 1); }

        const unsigned short* Ac = LB + cur * 16384;
        const unsigned short* Bc = LB + cur * 16384 + 8192;
        #pragma unroll
        for (int ks = 0; ks < 2; ++ks) {
            bf16x8 af[4], bfr[4];
            #pragma unroll
            for (int i = 0; i < 4; ++i) {
                const int row = wr * 64 + i * 16 + l15;
                af[i] = *(const bf16x8*)&Ac[row * 64 +
                            (((ks * 4 + quad) ^ (row & 7)) << 3)];
            }
            #pragma unroll
            for (int j = 0; j < 4; ++j) {
                const int nrw = wc * 64 + j * 16 + l15;
                bfr[j] = *(const bf16x8*)&Bc[nrw * 64 +
                            (((ks * 4 + quad) ^ (nrw & 7)) << 3)];
            }
            #pragma unroll
            for (int i = 0; i < 4; ++i)
                #pragma unroll
                for (int j = 0; j < 4; ++j)
                    acc[i][j] = MFMA16(af[i], bfr[j], acc[i][j]);
        }
        if (more) CVT_WRITE_A(av, nxt);
        __syncthreads();    // drains next-tile gload_lds (vm) + A writes (lgkm)
    }
    #undef STAGE_B
    #undef LOAD_A
    #undef CVT_WRITE_A

    const int bb = m0 >> 11, s0 = m0 & (S_ - 1);
    if (!VT) {
        #pragma unroll
        for (int i = 0; i < 4; ++i)
            #pragma unroll
            for (int r = 0; r < 4; ++r) {
                const int s = s0 + wr * 64 + i * 16 + quad * 4 + r;
                #pragma unroll
                for (int j = 0; j < 4; ++j) {
                    const int nn = n0 + wc * 64 + j * 16 + l15;
                    const int h = nn >> 6, d = nn & 63;
                    float val = acc[i][j][r] + bias[nn];
                    if (bias2) val += bias2[nn];
                    Y[(((size_t)bb * NH_ + h) * S_ + s) * D_ + d] = f2bf(val);
                }
            }
    } else {
        __syncthreads();
        #pragma unroll
        for (int i = 0; i < 4; ++i)
            #pragma unroll
            for (int r = 0; r < 4; ++r) {
                const int ml = wr * 64 + i * 16 + quad * 4 + r;
                #pragma unroll
                for (int j = 0; j < 4; ++j) {
                    const int nl = wc * 64 + j * 16 + l15;
                    LB[nl * 136 + ml] = f2bf(acc[i][j][r] + bias[n0 + nl]);
                }
            }
        __syncthreads();
        const int nr = t >> 1, half = t & 1;
        const int nn = n0 + nr, h = nn >> 6, d = nn & 63;
        const size_t vbase = (((size_t)bb * NH_ + h) * D_ + d) * S_ + s0 + half * 64;
        #pragma unroll
        for (int i = 0; i < 16; ++i)
            *(ushort4*)(Y + vbase + i * 4) =
                *(const ushort4*)&LB[nr * 136 + half * 64 + i * 4];
    }
}

// ---------------------------------------------------------------------------
// MFMA flash attention v3 (unchanged): 32x32x16 MFMA + fully in-register P.
// ---------------------------------------------------------------------------
__global__ __launch_bounds__(256) void attn_mfma(
    unsigned short* QHd,
    const unsigned short* __restrict__ Kh, const unsigned short* __restrict__ Vt,
    const int* __restrict__ mask)
{
    const int b = blockIdx.z, h = blockIdx.y;
    const int q0 = blockIdx.x * 128;
    const int t = threadIdx.x;
    const int w = t >> 6, lane = t & 63;
    const int hi = lane >> 5, l31 = lane & 31;

    __shared__ __align__(16) unsigned short KsL[2 * 4096];  // [2][64 key][64 d] swz
    __shared__ __align__(16) unsigned short VsL[2 * 4096];  // [2][64 d][64 key] swz
    __shared__ float mskf[S_];                              // -1e9 / 0 per key

    const size_t head = ((size_t)b * NH_ + h) * S_;
    unsigned short* Qbase = QHd + head * D_;
    const unsigned short* Kbase = Kh + head * D_;
    const unsigned short* Vbase = Vt + head * D_;   // [d][s] per head

    for (int i = t; i < S_; i += 256)
        mskf[i] = (mask[b * S_ + i] == 0) ? -1e9f : 0.f;

    bf16x8 qf[4];
    #pragma unroll
    for (int ks = 0; ks < 4; ++ks)
        qf[ks] = *(const bf16x8*)(
            Qbase + (size_t)(q0 + w * 32 + l31) * D_ + ks * 16 + hi * 8);

    f32x16 O0, O1;
    #pragma unroll
    for (int i = 0; i < 16; ++i) { O0[i] = 0.f; O1[i] = 0.f; }
    float lsum = 0.f;
    const float SC2 = 0.125f * 1.44269504089f;      // 1/sqrt(D) * log2(e)

    #define STAGE(kt_) do {                                                        \
        const int bf_ = (kt_) & 1, k0_ = (kt_) * 64;                               \
        _Pragma("unroll")                                                          \
        for (int i_ = 0; i_ < 2; ++i_) {                                           \
            const int c_ = w * 2 + i_;                                             \
            const int u_ = c_ * 64 + lane;                                         \
            const int row_ = u_ >> 3;                                              \
            const int sc_ = ((u_ & 7) ^ (row_ & 7)) << 3;                          \
            gl_lds16(Kbase + (size_t)(k0_ + row_) * D_ + sc_,                      \
                     KsL + bf_ * 4096 + c_ * 512);                                 \
            gl_lds16(Vbase + (size_t)row_ * S_ + k0_ + sc_,                        \
                     VsL + bf_ * 4096 + c_ * 512);                                 \
        }                                                                          \
    } while (0)

    STAGE(0);
    __syncthreads();

    for (int kt = 0; kt < S_ / 64; ++kt) {
        const int bf = kt & 1;
        const int k0 = kt * 64;
        if (kt + 1 < S_ / 64) STAGE(kt + 1);

        bf16x8 pfrag[4];                 // PV B-frags, ks = 0..3 (16 keys each)
        #pragma unroll
        for (int kb = 0; kb < 2; ++kb) {
            f32x16 acc;
            #pragma unroll
            for (int i = 0; i < 16; ++i) acc[i] = 0.f;
            const int krow = kb * 32 + l31;
            const unsigned short* Kb = KsL + bf * 4096 + krow * 64;
            const int rwk = krow & 7;
            __builtin_amdgcn_s_setprio(1);
            #pragma unroll
            for (int ks = 0; ks < 4; ++ks) {
                const bf16x8 kf = *(const bf16x8*)&Kb[(((ks * 2 + hi) ^ rwk) << 3)];
                acc = MFMA32(kf, qf[ks], acc);
            }
            __builtin_amdgcn_s_setprio(0);
            float p[16];
            #pragma unroll
            for (int bq = 0; bq < 4; ++bq) {
                const float4 ms4 = *(const float4*)&mskf[k0 + kb * 32 + bq * 8 + hi * 4];
                p[4 * bq + 0] = __builtin_amdgcn_exp2f(fmaf(acc[4 * bq + 0], SC2, ms4.x));
                p[4 * bq + 1] = __builtin_amdgcn_exp2f(fmaf(acc[4 * bq + 1], SC2, ms4.y));
                p[4 * bq + 2] = __builtin_amdgcn_exp2f(fmaf(acc[4 * bq + 2], SC2, ms4.z));
                p[4 * bq + 3] = __builtin_amdgcn_exp2f(fmaf(acc[4 * bq + 3], SC2, ms4.w));
            }
            lsum += ((p[0] + p[1]) + (p[2] + p[3])) + ((p[4] + p[5]) + (p[6] + p[7]))
                  + ((p[8] + p[9]) + (p[10] + p[11])) + ((p[12] + p[13]) + (p[14] + p[15]));
            unsigned pkv[8];
            #pragma unroll
            for (int bq = 0; bq < 4; ++bq) {
                pkv[2 * bq + 0] = pk2(p[4 * bq + 0], p[4 * bq + 1]);
                pkv[2 * bq + 1] = pk2(p[4 * bq + 2], p[4 * bq + 3]);
            }
            #pragma unroll
            for (int ksl = 0; ksl < 2; ++ksl) {
                unsigned m0 = pkv[4 * ksl + 0], m2 = pkv[4 * ksl + 2];
                asm volatile("v_permlane32_swap_b32 %0, %1" : "+v"(m0), "+v"(m2));
                unsigned m1 = pkv[4 * ksl + 1], m3 = pkv[4 * ksl + 3];
                asm volatile("v_permlane32_swap_b32 %0, %1" : "+v"(m1), "+v"(m3));
                union { unsigned u[4]; bf16x8 v; } pu;
                pu.u[0] = m0; pu.u[1] = m1; pu.u[2] = m2; pu.u[3] = m3;
                pfrag[kb * 2 + ksl] = pu.v;
            }
        }
        __builtin_amdgcn_s_setprio(1);
        #pragma unroll
        for (int dblk = 0; dblk < 2; ++dblk) {
            const int vrow = dblk * 32 + l31;
            const unsigned short* Vb = VsL + bf * 4096 + vrow * 64;
            const int rwv = vrow & 7;
            #pragma unroll
            for (int ks = 0; ks < 4; ++ks) {
                const bf16x8 vf = *(const bf16x8*)&Vb[(((ks * 2 + hi) ^ rwv) << 3)];
                if (dblk == 0) O0 = MFMA32(vf, pfrag[ks], O0);
                else           O1 = MFMA32(vf, pfrag[ks], O1);
            }
        }
        __builtin_amdgcn_s_setprio(0);
        __syncthreads();                        // single barrier per tile
    }
    #undef STAGE

    lsum += __shfl_xor(lsum, 32, 64);
    const float inv = 1.f / lsum;

    unsigned short* Orow = Qbase + (size_t)(q0 + w * 32 + l31) * D_;
    #pragma unroll
    for (int dblk = 0; dblk < 2; ++dblk) {
        #pragma unroll
        for (int bq = 0; bq < 4; ++bq) {
            const float v0 = (dblk ? O1[4 * bq + 0] : O0[4 * bq + 0]) * inv;
            const float v1 = (dblk ? O1[4 * bq + 1] : O0[4 * bq + 1]) * inv;
            const float v2 = (dblk ? O1[4 * bq + 2] : O0[4 * bq + 2]) * inv;
            const float v3 = (dblk ? O1[4 * bq + 3] : O0[4 * bq + 3]) * inv;
            uint2 st; st.x = pk2(v0, v1); st.y = pk2(v2, v3);
            *(uint2*)&Orow[dblk * 32 + bq * 8 + hi * 4] = st;
        }
    }
}

// ---------------------------------------------------------------------------
// MFMA output GEMM v3: Out_f32[m,n] = Hd_bf16(head-major)@Wo + bo.
// Both tiles gload_lds; DOUBLE-BUFFERED, one barrier per K-step.
// LDS 48KB -> 3 blocks/CU.
// ---------------------------------------------------------------------------
__global__ __launch_bounds__(256) void out_mfma(
    const unsigned short* __restrict__ Hd, const unsigned short* __restrict__ Wot,
    const float* __restrict__ bias, float* __restrict__ Out)
{
    __shared__ __align__(16) unsigned short As2[2][8192];   // [128][64] swz
    __shared__ __align__(16) unsigned short Bs2[2][4096];   // [64][64] swz
    const int t = threadIdx.x;
    const int w = t >> 6, lane = t & 63;
    const int quad = lane >> 4, l15 = lane & 15;
    const int wr = w >> 1, wc = w & 1;
    const int m0 = blockIdx.x * 128, n0 = blockIdx.y * 64;
    const int bb = m0 >> 11, s0 = m0 & (S_ - 1);

    const f32x4 zero = {0.f, 0.f, 0.f, 0.f};
    f32x4 acc[4][2];
    #pragma unroll
    for (int i = 0; i < 4; ++i)
        #pragma unroll
        for (int j = 0; j < 2; ++j) acc[i][j] = zero;

    #define OSTAGE(s_, bfx_) do {                                              \
        const int hk_ = (s_);                                                  \
        const unsigned short* Ab_ = Hd + (((size_t)bb * NH_ + hk_) * S_ + s0)  \
                                    * D_;                                      \
        _Pragma("unroll")                                                      \
        for (int i_ = 0; i_ < 4; ++i_) {                                       \
            const int c_ = w * 4 + i_, u_ = c_ * 64 + lane, row_ = u_ >> 3;    \
            const int sc_ = ((u_ & 7) ^ (row_ & 7)) << 3;                      \
            gl_lds16(Ab_ + (size_t)row_ * D_ + sc_, As2[bfx_] + c_ * 512);     \
        }                                                                      \
        _Pragma("unroll")                                                      \
        for (int i_ = 0; i_ < 2; ++i_) {                                       \
            const int c_ = w * 2 + i_, u_ = c_ * 64 + lane, row_ = u_ >> 3;    \
            const int sc_ = ((u_ & 7) ^ (row_ & 7)) << 3;                      \
            gl_lds16(Wot + (size_t)(n0 + row_) * H_ + hk_ * 64 + sc_,          \
                     Bs2[bfx_] + c_ * 512);                                    \
        }                                                                      \
    } while (0)

    OSTAGE(0, 0);
    __syncthreads();

    for (int s = 0; s < 8; ++s) {
        const int cur = s & 1;
        if (s + 1 < 8) OSTAGE(s + 1, cur ^ 1);
        #pragma unroll
        for (int ks = 0; ks < 2; ++ks) {
            bf16x8 af[4], bfr[2];
            #pragma unroll
            for (int i = 0; i < 4; ++i) {
                const int row = wr * 64 + i * 16 + l15;
                af[i] = *(const bf16x8*)&As2[cur][row * 64 +
                            (((ks * 4 + quad) ^ (row & 7)) << 3)];
            }
            #pragma unroll
            for (int j = 0; j < 2; ++j) {
                const int nrw = wc * 32 + j * 16 + l15;
                bfr[j] = *(const bf16x8*)&Bs2[cur][nrw * 64 +
                            (((ks * 4 + quad) ^ (nrw & 7)) << 3)];
            }
            #pragma unroll
            for (int i = 0; i < 4; ++i)
                #pragma unroll
                for (int j = 0; j < 2; ++j)
                    acc[i][j] = MFMA16(af[i], bfr[j], acc[i][j]);
        }
        __syncthreads();    // drains next-tile gload_lds; one barrier per step
    }
    #undef OSTAGE

    #pragma unroll
    for (int i = 0; i < 4; ++i)
        #pragma unroll
        for (int r = 0; r < 4; ++r) {
            const int m = m0 + wr * 64 + i * 16 + quad * 4 + r;
            #pragma unroll
            for (int j = 0; j < 2; ++j) {
                const int n = n0 + wc * 32 + j * 16 + l15;
                Out[(size_t)m * H_ + n] = acc[i][j][r] + bias[n];
            }
        }
}

// ---------------------------------------------------------------------------
__global__ void fill_kernel(float* __restrict__ out, float val, int n) {
    const int i = blockIdx.x * 256 + threadIdx.x;
    if (i < n) out[i] = val;
}

// ---------------------------------------------------------------------------
extern "C" void kernel_launch(void* const* d_in, const int* in_sizes, int n_in,
                              void* d_out, int out_size, void* d_ws, size_t ws_size,
                              hipStream_t stream) {
    const float* q   = (const float*)d_in[0];
    const float* k   = (const float*)d_in[1];
    const float* v   = (const float*)d_in[2];
    const float* k_b = (const float*)d_in[3];
    const int*   msk = (const int*)d_in[4];
    const float* Wq  = (const float*)d_in[5];
    const float* bq  = (const float*)d_in[6];
    const float* Wk  = (const float*)d_in[7];
    const float* bk  = (const float*)d_in[8];
    const float* Wv  = (const float*)d_in[9];
    const float* bv  = (const float*)d_in[10];
    const float* Wkb = (const float*)d_in[11];
    const float* bkb = (const float*)d_in[12];
    const float* Wo  = (const float*)d_in[13];
    const float* bo  = (const float*)d_in[14];
    float* out = (float*)d_out;

    const size_t PER  = (size_t)B_ * NH_ * S_ * D_;
    const size_t NEED = 3 * PER * sizeof(unsigned short);   // 24 MiB (proven)
    if (ws_size < NEED) {   // tripwire (dead path)
        fill_kernel<<<(out_size + 255) / 256, 256, 0, stream>>>(
            out, (float)((ws_size >> 20) + 2), out_size);
        return;
    }
    unsigned short* wsh = (unsigned short*)d_ws;
    unsigned short* Qf  = wsh;              // Q head-major; becomes Hd after attn
    unsigned short* Kf  = wsh + PER;        // K' head-major; Wo_t scratch after attn
    unsigned short* Vf  = wsh + 2 * PER;    // V transposed [b,h,d,s]

    // d_out doubles as scratch for the 4 projection weights until out_mfma.
    unsigned short* Wt = (unsigned short*)d_out;

    dim3 gw(8, 8, 4);
    prep_w<<<gw, 256, 0, stream>>>(Wq, Wk, Wkb, Wv, Wt);

    dim3 gp((B_ * S_) / 128, H_ / 128, 3);  // 64 x 4 x 3
    proj_all<<<gp, 256, 0, stream>>>(q, k, v, k_b, Wt, bq, bk, bkb, bv, Qf, Kf, Vf);

    dim3 ga(S_ / 128, NH_, B_);             // 16 x 8 x 4
    attn_mfma<<<ga, 256, 0, stream>>>(Qf, Kf, Vf, msk);

    // Kf is dead after attn: reuse it for transposed Wo.
    dim3 gw1(8, 8, 1);
    prep_w<<<gw1, 256, 0, stream>>>(Wo, Wo, Wo, Wo, Kf);

    dim3 go((B_ * S_) / 128, H_ / 64, 1);   // 64 x 8
    out_mfma<<<go, 256, 0, stream>>>(Qf, Kf, bo, out);
}

// Round 5
// 232.058 us; speedup vs baseline: 1.0551x; 1.0551x over previous
//
#include <hip/hip_runtime.h>
#include <hip/hip_bf16.h>
#include <math.h>

#define B_  4
#define S_  2048
#define H_  512
#define NH_ 8
#define D_  64

typedef __attribute__((ext_vector_type(8))) short bf16x8;   // 8 bf16 = 4 VGPR
typedef __attribute__((ext_vector_type(4))) float f32x4;
typedef __attribute__((ext_vector_type(16))) float f32x16;
#define MFMA16(a, b, c) __builtin_amdgcn_mfma_f32_16x16x32_bf16(a, b, c, 0, 0, 0)
#define MFMA32(a, b, c) __builtin_amdgcn_mfma_f32_32x32x16_bf16(a, b, c, 0, 0, 0)

__device__ __forceinline__ unsigned short f2bf(float f) {
    union { float f; unsigned int i; } x; x.f = f;
    unsigned int i = x.i;
    i += 0x7fffu + ((i >> 16) & 1u);
    return (unsigned short)(i >> 16);
}
// packed fp32 pair -> bf16 pair (RNE), lo in low 16 bits
__device__ __forceinline__ unsigned int pk2(float lo, float hi) {
    union { __hip_bfloat162 h; unsigned int u; } c;
    c.h = __float22bfloat162_rn(make_float2(lo, hi));
    return c.u;
}
// async global->LDS, 16 B per lane; lds ptr must be wave-uniform
__device__ __forceinline__ void gl_lds16(const void* g, void* l) {
    __builtin_amdgcn_global_load_lds(
        (const __attribute__((address_space(1))) unsigned int*)g,
        (__attribute__((address_space(3))) unsigned int*)l, 16, 0, 0);
}

// ---------------------------------------------------------------------------
// Weight prep: transpose+convert 512x512 fp32 W -> bf16 Wt[n][k] (n-major).
// ---------------------------------------------------------------------------
__global__ __launch_bounds__(256) void prep_w(
    const float* __restrict__ W0, const float* __restrict__ W1,
    const float* __restrict__ W2, const float* __restrict__ W3,
    unsigned short* __restrict__ Wt)
{
    const float* Ws[4] = {W0, W1, W2, W3};
    const float* W = Ws[blockIdx.z];
    unsigned short* Y = Wt + (size_t)blockIdx.z * H_ * H_;
    __shared__ float Tl[64][68];
    const int t = threadIdx.x;
    const int k0 = blockIdx.y * 64, n0 = blockIdx.x * 64;
    #pragma unroll
    for (int i = 0; i < 4; ++i) {
        const int e = (t + 256 * i) * 4;
        const int r = e >> 6, c = e & 63;
        const float4 a = *(const float4*)(W + (size_t)(k0 + r) * H_ + n0 + c);
        Tl[c + 0][r] = a.x; Tl[c + 1][r] = a.y;
        Tl[c + 2][r] = a.z; Tl[c + 3][r] = a.w;
    }
    __syncthreads();
    #pragma unroll
    for (int i = 0; i < 4; ++i) {
        const int e = (t + 256 * i) * 4;
        const int n = e >> 6, c = e & 63;
        uint2 p;
        p.x = pk2(Tl[n][c + 0], Tl[n][c + 1]);
        p.y = pk2(Tl[n][c + 2], Tl[n][c + 3]);
        *(uint2*)(Y + (size_t)(n0 + n) * H_ + k0 + c) = p;
    }
}

// ---------------------------------------------------------------------------
// Fused projections (R3-proven version): z=0 Q, z=1 K (dual), z=2 V
// (transposed epilogue). Tile 128x128, K-step 64, 2x2 wave quadrants.
// B via global_load_lds + pre-swizzled source; A fp32->bf16 swizzled write.
// Single-buffered (dbuf regressed in R4: 64KB LDS halved occupancy).
// ---------------------------------------------------------------------------
__global__ __launch_bounds__(256, 3) void proj_all(
    const float* __restrict__ q,  const float* __restrict__ k,
    const float* __restrict__ v,  const float* __restrict__ k_b,
    const unsigned short* __restrict__ Wt,
    const float* __restrict__ bq, const float* __restrict__ bk,
    const float* __restrict__ bkb,const float* __restrict__ bv,
    unsigned short* __restrict__ Qf, unsigned short* __restrict__ Kf,
    unsigned short* __restrict__ Vf)
{
    __shared__ __align__(16) unsigned short LB[17408];
    unsigned short* As = LB;            // 8192 halfs
    unsigned short* Bs = LB + 8192;     // 8192 halfs

    const int z = blockIdx.z;
    const float *X, *bias, *X2 = nullptr, *bias2 = nullptr;
    const unsigned short *Wa, *Wb = nullptr;
    unsigned short* Y;
    bool VT = false;
    const size_t WSZ = (size_t)H_ * H_;
    if (z == 0)      { X = q; Wa = Wt;           bias = bq; Y = Qf; }
    else if (z == 1) { X = k; Wa = Wt + WSZ;     bias = bk;
                       X2 = k_b; Wb = Wt + 2 * WSZ; bias2 = bkb; Y = Kf; }
    else             { X = v; Wa = Wt + 3 * WSZ; bias = bv; Y = Vf; VT = true; }

    const int t = threadIdx.x;
    const int w = t >> 6, lane = t & 63;
    const int quad = lane >> 4, l15 = lane & 15;
    const int wr = w >> 1, wc = w & 1;
    const int m0 = blockIdx.x * 128, n0 = blockIdx.y * 128;

    const f32x4 zero = {0.f, 0.f, 0.f, 0.f};
    f32x4 acc[4][4];
    #pragma unroll
    for (int i = 0; i < 4; ++i)
        #pragma unroll
        for (int j = 0; j < 4; ++j) acc[i][j] = zero;

    const int npass = (X2 != nullptr) ? 2 : 1;
    for (int pass = 0; pass < npass; ++pass) {
        const float* Xp = pass ? X2 : X;
        const unsigned short* Wp = pass ? Wb : Wa;
        for (int kb0 = 0; kb0 < H_; kb0 += 64) {
            __syncthreads();
            #pragma unroll
            for (int i = 0; i < 4; ++i) {
                const int c = w * 4 + i;
                const int u = c * 64 + lane;
                const int row = u >> 3;
                const int sc  = ((u & 7) ^ (row & 7)) << 3;
                gl_lds16(Wp + (size_t)(n0 + row) * H_ + kb0 + sc, Bs + c * 512);
            }
            float4 av[8];
            #pragma unroll
            for (int i = 0; i < 8; ++i) {
                const int e = (t + 256 * i) * 4;
                av[i] = *(const float4*)(Xp + (size_t)(m0 + (e >> 6)) * H_ + kb0 + (e & 63));
            }
            #pragma unroll
            for (int i = 0; i < 8; ++i) {
                const int e = (t + 256 * i) * 4;
                const int row = e >> 6, kc = e & 63;
                uint2 p; p.x = pk2(av[i].x, av[i].y); p.y = pk2(av[i].z, av[i].w);
                *(uint2*)&As[row * 64 + ((((kc >> 3) ^ (row & 7)) << 3) | (kc & 7))] = p;
            }
            __syncthreads();
            #pragma unroll
            for (int ks = 0; ks < 2; ++ks) {
                bf16x8 af[4], bfr[4];
                #pragma unroll
                for (int i = 0; i < 4; ++i) {
                    const int row = wr * 64 + i * 16 + l15;
                    af[i] = *(const bf16x8*)&As[row * 64 +
                                (((ks * 4 + quad) ^ (row & 7)) << 3)];
                }
                #pragma unroll
                for (int j = 0; j < 4; ++j) {
                    const int nrw = wc * 64 + j * 16 + l15;
                    bfr[j] = *(const bf16x8*)&Bs[nrw * 64 +
                                (((ks * 4 + quad) ^ (nrw & 7)) << 3)];
                }
                #pragma unroll
                for (int i = 0; i < 4; ++i)
                    #pragma unroll
                    for (int j = 0; j < 4; ++j)
                        acc[i][j] = MFMA16(af[i], bfr[j], acc[i][j]);
            }
        }
    }

    const int bb = m0 >> 11, s0 = m0 & (S_ - 1);
    if (!VT) {
        #pragma unroll
        for (int i = 0; i < 4; ++i)
            #pragma unroll
            for (int r = 0; r < 4; ++r) {
                const int s = s0 + wr * 64 + i * 16 + quad * 4 + r;
                #pragma unroll
                for (int j = 0; j < 4; ++j) {
                    const int nn = n0 + wc * 64 + j * 16 + l15;
                    const int h = nn >> 6, d = nn & 63;
                    float val = acc[i][j][r] + bias[nn];
                    if (bias2) val += bias2[nn];
                    Y[(((size_t)bb * NH_ + h) * S_ + s) * D_ + d] = f2bf(val);
                }
            }
    } else {
        __syncthreads();
        #pragma unroll
        for (int i = 0; i < 4; ++i)
            #pragma unroll
            for (int r = 0; r < 4; ++r) {
                const int ml = wr * 64 + i * 16 + quad * 4 + r;
                #pragma unroll
                for (int j = 0; j < 4; ++j) {
                    const int nl = wc * 64 + j * 16 + l15;
                    LB[nl * 136 + ml] = f2bf(acc[i][j][r] + bias[n0 + nl]);
                }
            }
        __syncthreads();
        const int nr = t >> 1, half = t & 1;
        const int nn = n0 + nr, h = nn >> 6, d = nn & 63;
        const size_t vbase = (((size_t)bb * NH_ + h) * D_ + d) * S_ + s0 + half * 64;
        #pragma unroll
        for (int i = 0; i < 16; ++i)
            *(ushort4*)(Y + vbase + i * 4) =
                *(const ushort4*)&LB[nr * 136 + half * 64 + i * 4];
    }
}

// ---------------------------------------------------------------------------
// MFMA flash attention v4: key-split waves for 2x TLP.
// Block = (b,h,64 q-rows), 4 waves; wave w owns q-group qg=w&1 (32 rows) and
// key-half kh=w>>1 (32 of each 64-key tile). Grid (32,8,4)=1024 blocks =
// 4 blocks/CU = 16 waves/CU (was 8). Per-wave chains halve:
// 4 QK MFMA + 16 exp2 + 2 pfrag + 4 PV MFMA per tile.
// End: cross-wave (key-half) O/lsum reduction through dead K/V LDS region.
// All per-tile math identical to R3's verified mapping with kb -> kh const.
// LDS: 16KB K + 16KB V + 8KB mask = 40KB -> 4 blocks/CU (160KB exactly).
// ---------------------------------------------------------------------------
__global__ __launch_bounds__(256, 4) void attn_mfma(
    unsigned short* QHd,
    const unsigned short* __restrict__ Kh, const unsigned short* __restrict__ Vt,
    const int* __restrict__ mask)
{
    const int b = blockIdx.z, h = blockIdx.y;
    const int q0 = blockIdx.x * 64;
    const int t = threadIdx.x;
    const int w = t >> 6, lane = t & 63;
    const int hi = lane >> 5, l31 = lane & 31;
    const int qg = w & 1, kh = w >> 1;

    __shared__ __align__(16) unsigned short KsL[2 * 4096];  // [2][64 key][64 d] swz
    __shared__ __align__(16) unsigned short VsL[2 * 4096];  // [2][64 d][64 key] swz
    __shared__ float mskf[S_];                              // -1e9 / 0 per key

    const size_t head = ((size_t)b * NH_ + h) * S_;
    unsigned short* Qbase = QHd + head * D_;
    const unsigned short* Kbase = Kh + head * D_;
    const unsigned short* Vbase = Vt + head * D_;   // [d][s] per head

    for (int i = t; i < S_; i += 256)
        mskf[i] = (mask[b * S_ + i] == 0) ? -1e9f : 0.f;

    // Q frags (B-operand): lane (hi,l31) holds Q[q0+qg*32+l31][16ks+8hi..+7]
    bf16x8 qf[4];
    #pragma unroll
    for (int ks = 0; ks < 4; ++ks)
        qf[ks] = *(const bf16x8*)(
            Qbase + (size_t)(q0 + qg * 32 + l31) * D_ + ks * 16 + hi * 8);

    f32x16 O0, O1;
    #pragma unroll
    for (int i = 0; i < 16; ++i) { O0[i] = 0.f; O1[i] = 0.f; }
    float lsum = 0.f;
    const float SC2 = 0.125f * 1.44269504089f;      // 1/sqrt(D) * log2(e)

    #define STAGE(kt_) do {                                                        \
        const int bf_ = (kt_) & 1, k0_ = (kt_) * 64;                               \
        _Pragma("unroll")                                                          \
        for (int i_ = 0; i_ < 2; ++i_) {                                           \
            const int c_ = w * 2 + i_;                                             \
            const int u_ = c_ * 64 + lane;                                         \
            const int row_ = u_ >> 3;                                              \
            const int sc_ = ((u_ & 7) ^ (row_ & 7)) << 3;                          \
            gl_lds16(Kbase + (size_t)(k0_ + row_) * D_ + sc_,                      \
                     KsL + bf_ * 4096 + c_ * 512);                                 \
            gl_lds16(Vbase + (size_t)row_ * S_ + k0_ + sc_,                        \
                     VsL + bf_ * 4096 + c_ * 512);                                 \
        }                                                                          \
    } while (0)

    STAGE(0);
    __syncthreads();

    for (int kt = 0; kt < S_ / 64; ++kt) {
        const int bf = kt & 1;
        const int k0 = kt * 64;
        if (kt + 1 < S_ / 64) STAGE(kt + 1);

        // ---- QK^T for own key-half: A = K rows (kh*32..+31), B = Q ----
        f32x16 acc;
        #pragma unroll
        for (int i = 0; i < 16; ++i) acc[i] = 0.f;
        const int krow = kh * 32 + l31;
        const unsigned short* Kb = KsL + bf * 4096 + krow * 64;
        const int rwk = krow & 7;
        __builtin_amdgcn_s_setprio(1);
        #pragma unroll
        for (int ks = 0; ks < 4; ++ks) {
            const bf16x8 kf = *(const bf16x8*)&Kb[(((ks * 2 + hi) ^ rwk) << 3)];
            acc = MFMA32(kf, qf[ks], acc);
        }
        __builtin_amdgcn_s_setprio(0);
        // ---- mask + exp2 (key = kh*32 + r4 + 8b + 4hi + k0) ----
        float p[16];
        #pragma unroll
        for (int bq = 0; bq < 4; ++bq) {
            const float4 ms4 = *(const float4*)&mskf[k0 + kh * 32 + bq * 8 + hi * 4];
            p[4 * bq + 0] = __builtin_amdgcn_exp2f(fmaf(acc[4 * bq + 0], SC2, ms4.x));
            p[4 * bq + 1] = __builtin_amdgcn_exp2f(fmaf(acc[4 * bq + 1], SC2, ms4.y));
            p[4 * bq + 2] = __builtin_amdgcn_exp2f(fmaf(acc[4 * bq + 2], SC2, ms4.z));
            p[4 * bq + 3] = __builtin_amdgcn_exp2f(fmaf(acc[4 * bq + 3], SC2, ms4.w));
        }
        lsum += ((p[0] + p[1]) + (p[2] + p[3])) + ((p[4] + p[5]) + (p[6] + p[7]))
              + ((p[8] + p[9]) + (p[10] + p[11])) + ((p[12] + p[13]) + (p[14] + p[15]));
        // ---- pack pairs ----
        unsigned pkv[8];
        #pragma unroll
        for (int bq = 0; bq < 4; ++bq) {
            pkv[2 * bq + 0] = pk2(p[4 * bq + 0], p[4 * bq + 1]);
            pkv[2 * bq + 1] = pk2(p[4 * bq + 2], p[4 * bq + 3]);
        }
        // ---- cross-half swap -> PV B-frags (keys [kh*32+ksl*16, +16)) ----
        bf16x8 pfrag[2];
        #pragma unroll
        for (int ksl = 0; ksl < 2; ++ksl) {
            unsigned m0 = pkv[4 * ksl + 0], m2 = pkv[4 * ksl + 2];
            asm volatile("v_permlane32_swap_b32 %0, %1" : "+v"(m0), "+v"(m2));
            unsigned m1 = pkv[4 * ksl + 1], m3 = pkv[4 * ksl + 3];
            asm volatile("v_permlane32_swap_b32 %0, %1" : "+v"(m1), "+v"(m3));
            union { unsigned u[4]; bf16x8 v; } pu;
            pu.u[0] = m0; pu.u[1] = m1; pu.u[2] = m2; pu.u[3] = m3;
            pfrag[ksl] = pu.v;
        }
        // ---- PV: O^T += mfma32(V rows, P) over own key-half ----
        __builtin_amdgcn_s_setprio(1);
        #pragma unroll
        for (int dblk = 0; dblk < 2; ++dblk) {
            const int vrow = dblk * 32 + l31;
            const unsigned short* Vb = VsL + bf * 4096 + vrow * 64;
            const int rwv = vrow & 7;
            #pragma unroll
            for (int ksl = 0; ksl < 2; ++ksl) {
                const bf16x8 vf =
                    *(const bf16x8*)&Vb[(((kh * 4 + ksl * 2 + hi) ^ rwv) << 3)];
                if (dblk == 0) O0 = MFMA32(vf, pfrag[ksl], O0);
                else           O1 = MFMA32(vf, pfrag[ksl], O1);
            }
        }
        __builtin_amdgcn_s_setprio(0);
        __syncthreads();                        // single barrier per tile
    }
    #undef STAGE

    // hi-halves of own key-half
    lsum += __shfl_xor(lsum, 32, 64);

    // ---- cross-wave (key-half) reduction through dead K/V LDS ----
    // wave (qg, kh=1) writes; wave (qg, kh=0) adds, normalizes, stores.
    // stride 33 dwords -> conflict-free.
    if (kh == 1) {
        float* R = qg ? (float*)VsL : (float*)KsL;
        #pragma unroll
        for (int i = 0; i < 16; ++i) R[lane * 33 + i]      = O0[i];
        #pragma unroll
        for (int i = 0; i < 16; ++i) R[lane * 33 + 16 + i] = O1[i];
        if (hi == 0) R[2112 + l31] = lsum;
    }
    __syncthreads();
    if (kh == 0) {
        const float* R = qg ? (const float*)VsL : (const float*)KsL;
        #pragma unroll
        for (int i = 0; i < 16; ++i) O0[i] += R[lane * 33 + i];
        #pragma unroll
        for (int i = 0; i < 16; ++i) O1[i] += R[lane * 33 + 16 + i];
        lsum += R[2112 + l31];
        const float inv = 1.f / lsum;

        unsigned short* Orow = Qbase + (size_t)(q0 + qg * 32 + l31) * D_;
        #pragma unroll
        for (int dblk = 0; dblk < 2; ++dblk) {
            #pragma unroll
            for (int bq = 0; bq < 4; ++bq) {
                const float v0 = (dblk ? O1[4 * bq + 0] : O0[4 * bq + 0]) * inv;
                const float v1 = (dblk ? O1[4 * bq + 1] : O0[4 * bq + 1]) * inv;
                const float v2 = (dblk ? O1[4 * bq + 2] : O0[4 * bq + 2]) * inv;
                const float v3 = (dblk ? O1[4 * bq + 3] : O0[4 * bq + 3]) * inv;
                uint2 st; st.x = pk2(v0, v1); st.y = pk2(v2, v3);
                *(uint2*)&Orow[dblk * 32 + bq * 8 + hi * 4] = st;
            }
        }
    }
}

// ---------------------------------------------------------------------------
// MFMA output GEMM (R3-proven version): Out_f32[m,n] = Hd@Wo + bo.
// Both tiles via global_load_lds with pre-swizzled sources. Single-buffered.
// ---------------------------------------------------------------------------
__global__ __launch_bounds__(256) void out_mfma(
    const unsigned short* __restrict__ Hd, const unsigned short* __restrict__ Wot,
    const float* __restrict__ bias, float* __restrict__ Out)
{
    __shared__ __align__(16) unsigned short As[8192];   // [128][64] swz
    __shared__ __align__(16) unsigned short Bs[4096];   // [64][64] swz
    const int t = threadIdx.x;
    const int w = t >> 6, lane = t & 63;
    const int quad = lane >> 4, l15 = lane & 15;
    const int wr = w >> 1, wc = w & 1;
    const int m0 = blockIdx.x * 128, n0 = blockIdx.y * 64;
    const int bb = m0 >> 11, s0 = m0 & (S_ - 1);

    const f32x4 zero = {0.f, 0.f, 0.f, 0.f};
    f32x4 acc[4][2];
    #pragma unroll
    for (int i = 0; i < 4; ++i)
        #pragma unroll
        for (int j = 0; j < 2; ++j) acc[i][j] = zero;

    for (int kb0 = 0; kb0 < H_; kb0 += 64) {
        const int hk = kb0 >> 6;
        const unsigned short* Ab = Hd + (((size_t)bb * NH_ + hk) * S_ + s0) * D_;
        __syncthreads();
        #pragma unroll
        for (int i = 0; i < 4; ++i) {
            const int c = w * 4 + i, u = c * 64 + lane, row = u >> 3;
            const int sc = ((u & 7) ^ (row & 7)) << 3;
            gl_lds16(Ab + (size_t)row * D_ + sc, As + c * 512);
        }
        #pragma unroll
        for (int i = 0; i < 2; ++i) {
            const int c = w * 2 + i, u = c * 64 + lane, row = u >> 3;
            const int sc = ((u & 7) ^ (row & 7)) << 3;
            gl_lds16(Wot + (size_t)(n0 + row) * H_ + kb0 + sc, Bs + c * 512);
        }
        __syncthreads();
        #pragma unroll
        for (int ks = 0; ks < 2; ++ks) {
            bf16x8 af[4], bfr[2];
            #pragma unroll
            for (int i = 0; i < 4; ++i) {
                const int row = wr * 64 + i * 16 + l15;
                af[i] = *(const bf16x8*)&As[row * 64 +
                            (((ks * 4 + quad) ^ (row & 7)) << 3)];
            }
            #pragma unroll
            for (int j = 0; j < 2; ++j) {
                const int nrw = wc * 32 + j * 16 + l15;
                bfr[j] = *(const bf16x8*)&Bs[nrw * 64 +
                            (((ks * 4 + quad) ^ (nrw & 7)) << 3)];
            }
            #pragma unroll
            for (int i = 0; i < 4; ++i)
                #pragma unroll
                for (int j = 0; j < 2; ++j)
                    acc[i][j] = MFMA16(af[i], bfr[j], acc[i][j]);
        }
    }
    #pragma unroll
    for (int i = 0; i < 4; ++i)
        #pragma unroll
        for (int r = 0; r < 4; ++r) {
            const int m = m0 + wr * 64 + i * 16 + quad * 4 + r;
            #pragma unroll
            for (int j = 0; j < 2; ++j) {
                const int n = n0 + wc * 32 + j * 16 + l15;
                Out[(size_t)m * H_ + n] = acc[i][j][r] + bias[n];
            }
        }
}

// ---------------------------------------------------------------------------
__global__ void fill_kernel(float* __restrict__ out, float val, int n) {
    const int i = blockIdx.x * 256 + threadIdx.x;
    if (i < n) out[i] = val;
}

// ---------------------------------------------------------------------------
extern "C" void kernel_launch(void* const* d_in, const int* in_sizes, int n_in,
                              void* d_out, int out_size, void* d_ws, size_t ws_size,
                              hipStream_t stream) {
    const float* q   = (const float*)d_in[0];
    const float* k   = (const float*)d_in[1];
    const float* v   = (const float*)d_in[2];
    const float* k_b = (const float*)d_in[3];
    const int*   msk = (const int*)d_in[4];
    const float* Wq  = (const float*)d_in[5];
    const float* bq  = (const float*)d_in[6];
    const float* Wk  = (const float*)d_in[7];
    const float* bk  = (const float*)d_in[8];
    const float* Wv  = (const float*)d_in[9];
    const float* bv  = (const float*)d_in[10];
    const float* Wkb = (const float*)d_in[11];
    const float* bkb = (const float*)d_in[12];
    const float* Wo  = (const float*)d_in[13];
    const float* bo  = (const float*)d_in[14];
    float* out = (float*)d_out;

    const size_t PER  = (size_t)B_ * NH_ * S_ * D_;
    const size_t NEED = 3 * PER * sizeof(unsigned short);   // 24 MiB (proven)
    if (ws_size < NEED) {   // tripwire (dead path)
        fill_kernel<<<(out_size + 255) / 256, 256, 0, stream>>>(
            out, (float)((ws_size >> 20) + 2), out_size);
        return;
    }
    unsigned short* wsh = (unsigned short*)d_ws;
    unsigned short* Qf  = wsh;              // Q head-major; becomes Hd after attn
    unsigned short* Kf  = wsh + PER;        // K' head-major; Wo_t scratch after attn
    unsigned short* Vf  = wsh + 2 * PER;    // V transposed [b,h,d,s]

    // d_out doubles as scratch for the 4 projection weights until out_mfma.
    unsigned short* Wt = (unsigned short*)d_out;

    dim3 gw(8, 8, 4);
    prep_w<<<gw, 256, 0, stream>>>(Wq, Wk, Wkb, Wv, Wt);

    dim3 gp((B_ * S_) / 128, H_ / 128, 3);  // 64 x 4 x 3
    proj_all<<<gp, 256, 0, stream>>>(q, k, v, k_b, Wt, bq, bk, bkb, bv, Qf, Kf, Vf);

    dim3 ga(S_ / 64, NH_, B_);              // 32 x 8 x 4 = 1024 blocks
    attn_mfma<<<ga, 256, 0, stream>>>(Qf, Kf, Vf, msk);

    // Kf is dead after attn: reuse it for transposed Wo.
    dim3 gw1(8, 8, 1);
    prep_w<<<gw1, 256, 0, stream>>>(Wo, Wo, Wo, Wo, Kf);

    dim3 go((B_ * S_) / 128, H_ / 64, 1);   // 64 x 8
    out_mfma<<<go, 256, 0, stream>>>(Qf, Kf, bo, out);
}